// Round 13
// baseline (573.133 us; speedup 1.0000x reference)
//
#include <hip/hip_runtime.h>

// Linear-chain CRF log-partition (backward DP), B=64, S=1024, T=128.
//
// r13 = r12 with the compile fix: __builtin_amdgcn_cvt_pkrtz returns an
// __fp16 ext-vector, not _Float16 -- bit_cast its native type to unsigned.
//
// Design: ONE WAVE per chain -- the barrier is gone. r7/r9/r11 all sat on a
// ~900-cyc fixed serial chain (write-drain + cross-SIMD s_barrier + LDS
// round-trip + zslot): halving the matvec (r11) saved only its predicted
// ~80 cyc, proving the chain, not issue, dominates. A single wave removes
// every element of that chain: DS ops are in-order within a wave (r4-proven)
// so publish->read needs no barrier and no explicit waitcnt; the dead-beat
// z = q[0] is a zero-staleness readfirstlane (no LDS round-trip).
// E = 2 rows x 128 cols packed f16 = 128 VGPRs/lane: fits ONLY under
// amdgpu_waves_per_eu(1,1) (r9's decisive result: VGPR budget 256+, table
// regs stay resident; without it the scheduler remats E every step --
// the r1-r8 flat ~1500 cyc/step pathology).
//
// Numerics (r7/r9/r11-proven dead-beat, zero staleness here):
//   z = readfirstlane(q.x)            (exact q[0] of the published state)
//   publish v' = q .* u .* e^{-GHAT}  (f16, unnormalized)
//   q <- (E v') * rcp(z);  Lam += GHAT + log z     (exact bookkeeping)
// Level: log q[0] = g_k - GHAT, bounded +-2; log v' in [-12, +2]: f16-safe.
//
// Per active step: cvt_pkrtz + ds_write_b32; 16x broadcast ds_read_b128
// (in-order DS pipe orders them after the write); 128x v_dot2_f32_f16
// (the 256-cyc issue floor); 6 adds; rcp-scale. exp(em) 2-ahead, 4-deep
// em prefetch (vmcnt never drained); W via per-64-step ballot mask (r11).

typedef _Float16 h2 __attribute__((ext_vector_type(2)));
typedef __fp16   hp2 __attribute__((ext_vector_type(2)));  // cvt_pkrtz return

#define B_  64
#define S_  1024
#define T_  128
#define PAD_IDX 0
#define EOS_IDX 3
#define BOT_IDX 1
#define GHAT         5.35f
#define EXP_NEG_GHAT 0.004736892f   // e^{-5.35}

#if defined(__has_builtin)
#if __has_builtin(__builtin_amdgcn_fdot2)
#define HAS_FDOT2 1
#endif
#endif

static __device__ __forceinline__ unsigned pack2(float a, float b) {
  hp2 h = __builtin_amdgcn_cvt_pkrtz(a, b);
  return __builtin_bit_cast(unsigned, h);
}

static __device__ __forceinline__ float dot2acc(unsigned eu, unsigned pu, float c) {
  h2 a = __builtin_bit_cast(h2, eu);
  h2 b = __builtin_bit_cast(h2, pu);
#ifdef HAS_FDOT2
  return __builtin_amdgcn_fdot2(a, b, c, false);
#else
  return fmaf((float)a.x, (float)b.x, fmaf((float)a.y, (float)b.y, c));
#endif
}

#define KEEPALIVE16(base) \
  asm volatile("" :: "v"(Eu[base+0]),  "v"(Eu[base+1]),  "v"(Eu[base+2]),  "v"(Eu[base+3]), \
                     "v"(Eu[base+4]),  "v"(Eu[base+5]),  "v"(Eu[base+6]),  "v"(Eu[base+7]), \
                     "v"(Eu[base+8]),  "v"(Eu[base+9]),  "v"(Eu[base+10]), "v"(Eu[base+11]), \
                     "v"(Eu[base+12]), "v"(Eu[base+13]), "v"(Eu[base+14]), "v"(Eu[base+15]))

__global__ __launch_bounds__(64)
__attribute__((amdgpu_waves_per_eu(1, 1)))
void crf_logz_kernel(
    const int*   __restrict__ W,
    const float* __restrict__ emissions,
    const float* __restrict__ transitions,
    float*       __restrict__ out)
{
  const int b  = blockIdx.x;
  const int l  = threadIdx.x;        // lane 0..63
  const int r0 = 2 * l;              // owns tag rows r0, r0+1 (all 128 cols)

  __shared__ __align__(16) unsigned vbuf[T_ / 2];   // 64 packed half2

  // ---- E rows r0, r0+1 as 128 packed f16 pairs (128 VGPRs; resident under
  //      waves_per_eu(1,1)). Eu[0..63] = row r0, Eu[64..127] = row r0+1.
  unsigned Eu[128];
  {
    const float2* ta = (const float2*)(transitions + (size_t)r0 * T_);
    const float2* tb = (const float2*)(transitions + (size_t)(r0 + 1) * T_);
    #pragma unroll
    for (int k = 0; k < 64; ++k) {
      float2 x = ta[k], y = tb[k];
      Eu[k]      = pack2(__expf(x.x), __expf(x.y));
      Eu[64 + k] = pack2(__expf(y.x), __expf(y.y));
    }
  }

  const int*    Wrow = W + b * S_;
  const float2* emb2 = (const float2*)(emissions + (size_t)b * S_ * T_) + l;

  float2 q;  q.x = 1.0f; q.y = 1.0f;   // exp-state; true Beta_r = log q + Lam
  float  Lam = 0.0f;

  // 4-deep em prefetch: slot0 holds consumed index i
  float2 e0 = emb2[(size_t)(S_ - 1) * 64];
  float2 e1 = emb2[(size_t)(S_ - 2) * 64];
  float2 e2 = emb2[(size_t)(S_ - 3) * 64];
  float2 e3 = emb2[(size_t)(S_ - 4) * 64];
  float2 us0, us1;
  us0.x = __expf(e0.x) * EXP_NEG_GHAT; us0.y = __expf(e0.y) * EXP_NEG_GHAT;
  us1.x = __expf(e1.x) * EXP_NEG_GHAT; us1.y = __expf(e1.y) * EXP_NEG_GHAT;

  for (int c = 15; c >= 0; --c) {
    // one vector load of 64 token ids -> uniform 64-bit activity mask (SGPRs)
    int wtok = Wrow[(c << 6) + l];
    unsigned long long m = __ballot((wtok != PAD_IDX) & (wtok != EOS_IDX));
    const int lo = (c == 0) ? 1 : 0;          // i==0 is never consumed

    for (int bit = 63; bit >= lo; --bit) {
      KEEPALIVE16(0);  KEEPALIVE16(16); KEEPALIVE16(32);  KEEPALIVE16(48);
      KEEPALIVE16(64); KEEPALIVE16(80); KEEPALIVE16(96);  KEEPALIVE16(112);

      const int i = (c << 6) + bit;           // consumed emission index
      int pf = i - 4; if (pf < 0) pf = 0;     // clamped tail re-read: harmless
      float2 en = emb2[(size_t)pf * 64];      // prefetch (vmcnt, never drained)

      const bool active = (long long)m < 0;   // top bit
      m <<= 1;

      if (active) {                           // wave-uniform branch
        // z = q[0] of the state being published -- exact, zero staleness
        float z = __builtin_bit_cast(float,
            __builtin_amdgcn_readfirstlane(__builtin_bit_cast(int, q.x)));
        // publish v' = q .* us (unnormalized)
        vbuf[l] = pack2(q.x * us0.x, q.y * us0.y);      // ds_write_b32
        asm volatile("" ::: "memory");        // compile-time order only; the
                                              // wave's DS pipe is in-order (r4)
        float rz = __builtin_amdgcn_rcpf(z);  // off-path while reads fly

        const uint4* vb = (const uint4*)vbuf;
        float aA0=0.f,aA1=0.f,aA2=0.f,aA3=0.f;
        float aB0=0.f,aB1=0.f,aB2=0.f,aB3=0.f;
        #pragma unroll
        for (int k = 0; k < 16; ++k) {
          uint4 pv = vb[k];                   // broadcast ds_read_b128
          aA0 = dot2acc(Eu[4*k+0],      pv.x, aA0);
          aA1 = dot2acc(Eu[4*k+1],      pv.y, aA1);
          aA2 = dot2acc(Eu[4*k+2],      pv.z, aA2);
          aA3 = dot2acc(Eu[4*k+3],      pv.w, aA3);
          aB0 = dot2acc(Eu[64+4*k+0],   pv.x, aB0);
          aB1 = dot2acc(Eu[64+4*k+1],   pv.y, aB1);
          aB2 = dot2acc(Eu[64+4*k+2],   pv.z, aB2);
          aB3 = dot2acc(Eu[64+4*k+3],   pv.w, aB3);
        }
        q.x = ((aA0 + aA1) + (aA2 + aA3)) * rz;
        q.y = ((aB0 + aB1) + (aB2 + aB3)) * rz;
        Lam += GHAT + __logf(z);              // exact compensation (off-path)
      }
      // shift prefetch pipeline
      e0 = e1; us0 = us1;
      e1 = e2;
      e2 = e3;
      e3 = en;
      us1.x = __expf(e1.x) * EXP_NEG_GHAT;
      us1.y = __expf(e1.y) * EXP_NEG_GHAT;
    }
  }

  // ---- epilogue: f_r = trans[BOT,r] + em[b,0,r] + log q_r + Lam
  float2 tb2 = *(const float2*)(transitions + BOT_IDX * T_ + r0);
  float f0 = tb2.x + e0.x + __logf(q.x);      // e0 ended as em[b,0,r0:r0+2]
  float f1 = tb2.y + e0.y + __logf(q.y);
  float mm = fmaxf(f0, f1);
  #pragma unroll
  for (int off = 32; off; off >>= 1) mm = fmaxf(mm, __shfl_xor(mm, off));
  float s = __expf(f0 - mm) + __expf(f1 - mm);
  #pragma unroll
  for (int off = 32; off; off >>= 1) s += __shfl_xor(s, off);
  if (l == 0) out[b] = Lam + mm + __logf(s);
}

extern "C" void kernel_launch(void* const* d_in, const int* in_sizes, int n_in,
                              void* d_out, int out_size, void* d_ws, size_t ws_size,
                              hipStream_t stream) {
  const int*   W     = (const int*)d_in[0];
  const float* em    = (const float*)d_in[1];
  const float* trans = (const float*)d_in[2];
  float*       out   = (float*)d_out;
  (void)in_sizes; (void)n_in; (void)out_size; (void)d_ws; (void)ws_size;
  crf_logz_kernel<<<B_, 64, 0, stream>>>(W, em, trans, out);
}